// Round 1
// baseline (72.551 us; speedup 1.0000x reference)
//
#include <hip/hip_runtime.h>
#include <hip/hip_bf16.h>
#include <stdint.h>

#define K_DIM 128
#define N_X   8192      // columns of x (the "n" / M dimension)
#define N_WO  8192      // 64*128 flattened (w,o) -> GEMM N dimension
#define OUT_TOTAL (8192UL * 64UL * 128UL)

typedef __attribute__((ext_vector_type(8))) short short8;   // 8 bf16 = 4 VGPR
typedef __attribute__((ext_vector_type(4))) float f32x4;

__device__ inline unsigned short f2bf(float f) {
    union { float f; unsigned u; } v; v.f = f;
    unsigned u = v.u;
    u += 0x7fffu + ((u >> 16) & 1u);   // round-to-nearest-even
    return (unsigned short)(u >> 16);
}

// Transpose+convert P[128][8192] f32 (k-major, inner contiguous) into
// MFMA fragment-linear bf16 blocks. Chunk c = ((t*4 + ks)*64 + l) is 16B:
//   elem j (0..7): P[ks*32 + (l>>4)*8 + j][t*16 + (l&15)]
// so in the GEMM a wave's lane l loads chunk (t,ks,l) and directly has the
// mfma_f32_16x16x32_bf16 A/B fragment for 16-row tile t, K-step ks.
__global__ __launch_bounds__(256) void prep_frag(const float* __restrict__ P,
                                                 uint4* __restrict__ Q) {
    int c  = blockIdx.x * 256 + threadIdx.x;   // 0 .. 131071
    int l  = c & 63;
    int ks = (c >> 6) & 3;
    int t  = c >> 8;
    int m  = t * 16 + (l & 15);
    int k0 = ks * 32 + ((l >> 4) << 3);
    const float* p = P + (size_t)k0 * N_X + m;
    unsigned short h[8];
#pragma unroll
    for (int j = 0; j < 8; ++j) h[j] = f2bf(p[(size_t)j * N_X]);
    uint4 q;
    q.x = (unsigned)h[0] | ((unsigned)h[1] << 16);
    q.y = (unsigned)h[2] | ((unsigned)h[3] << 16);
    q.z = (unsigned)h[4] | ((unsigned)h[5] << 16);
    q.w = (unsigned)h[6] | ((unsigned)h[7] << 16);
    Q[c] = q;
}

// Fragment-direct GEMM: C[m][n] = sum_k A[m][k]*B[k][n] (+128*bias[n&127]).
// A,B pre-laid-out in fragment-linear blocks (see prep_frag). No LDS.
__global__ __launch_bounds__(256) void gemm_frag(const short8* __restrict__ A,
                                                 const short8* __restrict__ B,
                                                 const float* __restrict__ bias,
                                                 float* __restrict__ out) {
    int bid = blockIdx.x;
    // bijective XCD swizzle (4096 % 8 == 0): consecutive blocks on one XCD
    int swz = (bid & 7) * 512 + (bid >> 3);
    int bm = swz >> 6, bn = swz & 63;

    int tid  = threadIdx.x;
    int lane = tid & 63;
    int w    = tid >> 6;
    int wr = w >> 1, wc = w & 1;
    int m0 = bm * 128 + wr * 64;
    int n0 = bn * 128 + wc * 64;
    int tm0 = m0 >> 4;   // 16-row tile indices
    int tn0 = n0 >> 4;

    f32x4 acc[4][4] = {};
#pragma unroll
    for (int ks = 0; ks < 4; ++ks) {
        short8 a[4], b[4];
#pragma unroll
        for (int i = 0; i < 4; ++i) {
            a[i] = A[((tm0 + i) * 4 + ks) * 64 + lane];
            b[i] = B[((tn0 + i) * 4 + ks) * 64 + lane];
        }
#pragma unroll
        for (int i = 0; i < 4; ++i)
#pragma unroll
            for (int j = 0; j < 4; ++j)
                acc[i][j] = __builtin_amdgcn_mfma_f32_16x16x32_bf16(
                    a[i], b[j], acc[i][j], 0, 0, 0);
    }

    // Epilogue: C/D layout col=lane&15, row=(lane>>4)*4+reg (m89/m91-verified)
    int cl = lane & 15, rg = (lane >> 4) << 2;
#pragma unroll
    for (int j = 0; j < 4; ++j) {
        int ncol = n0 + j * 16 + cl;
        float bv = 128.0f * bias[ncol & 127];
#pragma unroll
        for (int i = 0; i < 4; ++i) {
            int row = m0 + i * 16 + rg;
            float* po = out + (size_t)row * N_WO + ncol;
#pragma unroll
            for (int r = 0; r < 4; ++r)
                po[(size_t)r * N_WO] = acc[i][j][r] + bv;
        }
    }
}

// Correctness fallback if d_ws is too small for the transposed panels.
__global__ __launch_bounds__(256) void naive_kernel(const float* __restrict__ x,
                                                    const float* __restrict__ wgt,
                                                    const float* __restrict__ bias,
                                                    float* __restrict__ out) {
    size_t idx = (size_t)blockIdx.x * 256 + threadIdx.x;
    if (idx >= OUT_TOTAL) return;
    int n    = (int)(idx >> 13);
    int ncol = (int)(idx & 8191);
    float s = 0.f;
    for (int i = 0; i < K_DIM; ++i)
        s += x[(size_t)i * N_X + n] * wgt[(size_t)i * N_WO + ncol];
    out[idx] = s + 128.0f * bias[ncol & 127];
}

extern "C" void kernel_launch(void* const* d_in, const int* in_sizes, int n_in,
                              void* d_out, int out_size, void* d_ws, size_t ws_size,
                              hipStream_t stream) {
    const float* x    = (const float*)d_in[0];   // [128][8192]
    const float* wgt  = (const float*)d_in[1];   // [128][64*128]
    const float* bias = (const float*)d_in[2];   // [128]
    float* out = (float*)d_out;

    if (ws_size >= 4u * 1024u * 1024u) {
        uint4* wsA = (uint4*)d_ws;          // 2 MiB: x^T fragment-linear bf16
        uint4* wsB = wsA + 131072;          // 2 MiB: W   fragment-linear bf16
        prep_frag<<<512, 256, 0, stream>>>(x,   wsA);
        prep_frag<<<512, 256, 0, stream>>>(wgt, wsB);
        gemm_frag<<<4096, 256, 0, stream>>>((const short8*)wsA, (const short8*)wsB,
                                            bias, out);
    } else {
        naive_kernel<<<(unsigned)((OUT_TOTAL + 255) / 256), 256, 0, stream>>>(
            x, wgt, bias, out);
    }
}